// Round 1
// baseline (717.573 us; speedup 1.0000x reference)
//
#include <hip/hip_runtime.h>

typedef unsigned int  u32;
typedef unsigned short u16;
typedef __attribute__((ext_vector_type(8))) _Float16 h8;   // MFMA A/B frag: 8 fp16 = 4 VGPR
typedef __attribute__((ext_vector_type(4))) float    f4;   // MFMA C/D frag

#define RS   136   // padded row stride (fp16 elems) for 128-wide tiles: 272B -> 2-way LDS aliasing only
#define PRS  40    // padded row stride for PE tiles (K=18 padded to 32)
#define PIXB 128   // pixels per block (4 waves x 32 pixels)

__device__ __forceinline__ u16 f2h(float f) {
  _Float16 h = (_Float16)f;                  // v_cvt_f16_f32, RNE
  return __builtin_bit_cast(u16, h);
}
__device__ __forceinline__ float h2f(u16 u) {
  return (float)__builtin_bit_cast(_Float16, u);
}

// ---------------------------------------------------------------------------
// Prep: convert all weight matrices to fp16, TRANSPOSED to [out][in] ("B-frag
// wants k-contiguous per output column") and padded to the staged row stride.
// ws layout (fp16 elems): [0,5120)        vdeT   [128][40]  (k<18 valid)
//                         [5120 + i*17408) 11 x   [128][136] (vh0..2,hid00..12,headW0,headW1)
//                         [196608,198784)  head2T [16][136]  (n<4 valid)
// ---------------------------------------------------------------------------
__global__ __launch_bounds__(256) void rc_prep(
    const float* __restrict__ vde_W, const float* __restrict__ vh_W,
    const float* __restrict__ hid_W, const float* __restrict__ head_W0,
    const float* __restrict__ head_W1, const float* __restrict__ head_W2,
    u16* __restrict__ ws)
{
  const int VDE_N = 128 * PRS;          // 5120
  const int FULL  = 128 * RS;           // 17408
  const int TOT   = VDE_N + 11 * FULL + 16 * RS;  // 198784
  int i = blockIdx.x * 256 + threadIdx.x;
  if (i >= TOT) return;
  float val = 0.f;
  if (i < VDE_N) {
    int n = i / PRS, k = i - n * PRS;
    if (k < 18) val = vde_W[k * 128 + n];
  } else if (i < VDE_N + 11 * FULL) {
    int t = i - VDE_N;
    int j = t / FULL;
    int rr = t - j * FULL;
    int n = rr / RS, k = rr - n * RS;
    if (k < 128) {
      const float* src;
      if (j < 3)       src = vh_W  + j * 16384;        // vh_W[0][j]
      else if (j < 9)  src = hid_W + (j - 3) * 16384;  // hid_W flat [2*3][128][128]
      else if (j == 9) src = head_W0;
      else             src = head_W1;
      val = src[k * 128 + n];
    }
  } else {
    int t = i - (VDE_N + 11 * FULL);
    int n = t / RS, k = t - n * RS;
    if (k < 128 && n < 4) val = head_W2[k * 4 + n];
  }
  ws[i] = f2h(val);
}

// ---------------------------------------------------------------------------
// Main fused kernel. Block = 256 thr (4 waves), 128 pixels.
// Wave w owns pixels [32w, 32w+32). Per 128x128 layer per wave:
//   A-frags (2 Mtiles x 4 Ksteps) held in regs -> in-place X update is safe.
//   mfma_f32_16x16x32_f16; C layout col=lane&15(n), row=(lane>>4)*4+reg (m).
// Phase order: PE -> L0(vde) -> vh chain (X as scratch, vh captured to regs)
//              -> gather (X = barycentric embedding sum) -> hid/head chain.
// ---------------------------------------------------------------------------
__global__ __launch_bounds__(256, 2) void rc_main(
    const int*   __restrict__ vert,  const float* __restrict__ bary,
    const float* __restrict__ view,  const float* __restrict__ emb,
    const float* __restrict__ vde_b, const float* __restrict__ vh_b,
    const float* __restrict__ hid_b, const float* __restrict__ head_b0,
    const float* __restrict__ head_b1, const float* __restrict__ head_b2,
    const u16*   __restrict__ ws,    float* __restrict__ out)
{
  __shared__ __align__(16) u16 X  [PIXB * RS];   // 34816 B activations
  __shared__ __align__(16) u16 WL [128  * RS];   // 34816 B staged layer weights
  __shared__ __align__(16) u16 PEb[PIXB * PRS];  // 10240 B positional encoding

  const int tid  = threadIdx.x;
  const int lane = tid & 63;
  const int w    = tid >> 6;
  const int r    = lane & 15;       // n-within-tile (B/C col), also A row
  const int g    = lane >> 4;       // k-group / C row group
  const int pb   = w * 32;          // wave's first pixel row
  const size_t bpix = (size_t)blockIdx.x * PIXB;

  // ---- Phase PE: view-dir sin/cos encoding -> PEb (fp16, zero-padded to 40)
  if (tid < PIXB) {
    const float* vd = view + (bpix + tid) * 3;
    u32* pw = (u32*)&PEb[tid * PRS];
    const float SG0 = 6.28318530718f;   // 2pi / 0.9^0
    const float SG1 = 6.50777324f;      // 2pi / 0.9^(1/3)
    const float SG2 = 6.74038866f;      // 2pi / 0.9^(2/3)
#pragma unroll
    for (int i = 0; i < 3; ++i) {
      float x = vd[i];
      float s0 = __sinf(x * SG0), c0 = __cosf(x * SG0);
      float s1 = __sinf(x * SG1), c1 = __cosf(x * SG1);
      float s2 = __sinf(x * SG2), c2 = __cosf(x * SG2);
      // flat pe layout per i: [sin(s0,s1,s2), cos(c0,c1,c2)]
      pw[i * 3 + 0] = (u32)f2h(s0) | ((u32)f2h(s1) << 16);
      pw[i * 3 + 1] = (u32)f2h(s2) | ((u32)f2h(c0) << 16);
      pw[i * 3 + 2] = (u32)f2h(c1) | ((u32)f2h(c2) << 16);
    }
#pragma unroll
    for (int q = 9; q < 20; ++q) pw[q] = 0u;   // pad k=18..39 with zeros
  }

  // ---- L0: PE @ vde_W + vde_b (no relu) -> X
  __syncthreads();
  {
    const uint4* s4 = (const uint4*)ws;
    uint4* d4 = (uint4*)WL;
    for (int c = tid; c < 640; c += 256) d4[c] = s4[c];  // 128*40*2/16
  }
  __syncthreads();
  {
    h8 a0 = *(const h8*)&PEb[(pb +      r) * PRS + g * 8];
    h8 a1 = *(const h8*)&PEb[(pb + 16 + r) * PRS + g * 8];
#pragma unroll
    for (int nt = 0; nt < 8; ++nt) {
      h8 b = *(const h8*)&WL[(nt * 16 + r) * PRS + g * 8];
      f4 z = {0.f, 0.f, 0.f, 0.f};
      f4 acc0 = __builtin_amdgcn_mfma_f32_16x16x32_f16(a0, b, z, 0, 0, 0);
      f4 acc1 = __builtin_amdgcn_mfma_f32_16x16x32_f16(a1, b, z, 0, 0, 0);
      float bv = vde_b[nt * 16 + r];
#pragma unroll
      for (int j = 0; j < 4; ++j) {
        X[(pb +      g * 4 + j) * RS + nt * 16 + r] = f2h(acc0[j] + bv);
        X[(pb + 16 + g * 4 + j) * RS + nt * 16 + r] = f2h(acc1[j] + bv);
      }
    }
  }

  // ---- 11 full 128x128 layers: li 0..2 = vh MLP, 3..8 = hidden, 9..10 = head
  u32 vhp[2][8][2] = {};   // captured vh (fp16 pairs), li==2 -> li==5
#pragma unroll 1
  for (int li = 0; li < 11; ++li) {
    __syncthreads();                       // all waves done reading WL
    {
      const uint4* s4 = (const uint4*)(ws + 5120 + li * 17408);
      uint4* d4 = (uint4*)WL;
      for (int c = tid; c < 2176; c += 256) d4[c] = s4[c];
    }
    __syncthreads();
    const float* bias = (li < 3) ? (vh_b + li * 128)
                      : (li < 9) ? (hid_b + (li - 3) * 128)
                      : (li == 9) ? head_b0 : head_b1;
    const int mode = (li == 2) ? 1 : (li == 5) ? 2 : 0;  // 1=capture vh, 2=modulate

    h8 a[2][4];
#pragma unroll
    for (int mt = 0; mt < 2; ++mt)
#pragma unroll
      for (int ks = 0; ks < 4; ++ks)
        a[mt][ks] = *(const h8*)&X[(pb + mt * 16 + r) * RS + ks * 32 + g * 8];

#pragma unroll
    for (int nt = 0; nt < 8; ++nt) {
      h8 b[4];
#pragma unroll
      for (int ks = 0; ks < 4; ++ks)
        b[ks] = *(const h8*)&WL[(nt * 16 + r) * RS + ks * 32 + g * 8];
      f4 acc[2] = {{0.f,0.f,0.f,0.f},{0.f,0.f,0.f,0.f}};
#pragma unroll
      for (int ks = 0; ks < 4; ++ks) {
        acc[0] = __builtin_amdgcn_mfma_f32_16x16x32_f16(a[0][ks], b[ks], acc[0], 0, 0, 0);
        acc[1] = __builtin_amdgcn_mfma_f32_16x16x32_f16(a[1][ks], b[ks], acc[1], 0, 0, 0);
      }
      float bv = bias[nt * 16 + r];
#pragma unroll
      for (int mt = 0; mt < 2; ++mt) {
        float v0 = fmaxf(acc[mt][0] + bv, 0.f);
        float v1 = fmaxf(acc[mt][1] + bv, 0.f);
        float v2 = fmaxf(acc[mt][2] + bv, 0.f);
        float v3 = fmaxf(acc[mt][3] + bv, 0.f);
        if (mode == 1) {                       // vh = relu(out), keep in regs
          vhp[mt][nt][0] = (u32)f2h(v0) | ((u32)f2h(v1) << 16);
          vhp[mt][nt][1] = (u32)f2h(v2) | ((u32)f2h(v3) << 16);
        } else {
          if (mode == 2) {                     // h = relu(out) * vh
            v0 *= h2f((u16)(vhp[mt][nt][0] & 0xffffu));
            v1 *= h2f((u16)(vhp[mt][nt][0] >> 16));
            v2 *= h2f((u16)(vhp[mt][nt][1] & 0xffffu));
            v3 *= h2f((u16)(vhp[mt][nt][1] >> 16));
          }
          int base = (pb + mt * 16 + g * 4) * RS + nt * 16 + r;
          X[base]          = f2h(v0);
          X[base + RS]     = f2h(v1);
          X[base + 2 * RS] = f2h(v2);
          X[base + 3 * RS] = f2h(v3);
        }
      }
    }

    // ---- after vh capture: embedding gather+renorm+bary -> X (wave-private rows)
    if (li == 2) {
#pragma unroll 2
      for (int i = 0; i < 8; ++i) {
        int p = pb + g * 8 + i;                // 16-lane group g handles 8 pixels
        size_t gp = bpix + p;
        const int*   vi = vert + gp * 3;
        const float* by = bary + gp * 3;
        f4 va = {0.f,0.f,0.f,0.f}, vb = {0.f,0.f,0.f,0.f};
#pragma unroll
        for (int vt = 0; vt < 3; ++vt) {
          int id = vi[vt] + 1;
          const float* row = emb + (size_t)id * 128 + r * 8;  // lane r: 8 chans
          f4 e0 = *(const f4*)row;
          f4 e1 = *(const f4*)(row + 4);
          float ss = e0[0]*e0[0] + e0[1]*e0[1] + e0[2]*e0[2] + e0[3]*e0[3]
                   + e1[0]*e1[0] + e1[1]*e1[1] + e1[2]*e1[2] + e1[3]*e1[3];
          ss += __shfl_xor(ss, 1);             // reduce across the 16-lane group
          ss += __shfl_xor(ss, 2);
          ss += __shfl_xor(ss, 4);
          ss += __shfl_xor(ss, 8);
          float nrm = sqrtf(ss);
          float sc  = (nrm > 1.f) ? (1.f / (nrm + 1e-7f)) : 1.f;  // torch max_norm
          float wt  = by[vt] * sc;
#pragma unroll
          for (int j = 0; j < 4; ++j) { va[j] += wt * e0[j]; vb[j] += wt * e1[j]; }
        }
        h8 o;
#pragma unroll
        for (int j = 0; j < 4; ++j) { o[j] = (_Float16)va[j]; o[j+4] = (_Float16)vb[j]; }
        *(h8*)&X[p * RS + r * 8] = o;
      }
    }
  }

  // ---- L12: head_W2 (128 -> 4) + head_b2, no relu, write f32 output
  __syncthreads();
  {
    const uint4* s4 = (const uint4*)(ws + 196608);
    uint4* d4 = (uint4*)WL;
    for (int c = tid; c < 272; c += 256) d4[c] = s4[c];
  }
  __syncthreads();
  {
    h8 a[2][4];
#pragma unroll
    for (int mt = 0; mt < 2; ++mt)
#pragma unroll
      for (int ks = 0; ks < 4; ++ks)
        a[mt][ks] = *(const h8*)&X[(pb + mt * 16 + r) * RS + ks * 32 + g * 8];
    f4 acc0 = {0.f,0.f,0.f,0.f}, acc1 = {0.f,0.f,0.f,0.f};
#pragma unroll
    for (int ks = 0; ks < 4; ++ks) {
      h8 b = *(const h8*)&WL[r * RS + ks * 32 + g * 8];   // rows n=0..15 (n>=4 zero)
      acc0 = __builtin_amdgcn_mfma_f32_16x16x32_f16(a[0][ks], b, acc0, 0, 0, 0);
      acc1 = __builtin_amdgcn_mfma_f32_16x16x32_f16(a[1][ks], b, acc1, 0, 0, 0);
    }
    if (r < 4) {
      float bv = head_b2[r];
#pragma unroll
      for (int j = 0; j < 4; ++j) {
        out[(bpix + pb +      g * 4 + j) * 4 + r] = acc0[j] + bv;
        out[(bpix + pb + 16 + g * 4 + j) * 4 + r] = acc1[j] + bv;
      }
    }
  }
}

// ---------------------------------------------------------------------------
extern "C" void kernel_launch(void* const* d_in, const int* in_sizes, int n_in,
                              void* d_out, int out_size, void* d_ws, size_t ws_size,
                              hipStream_t stream) {
  const int*   vert    = (const int*)  d_in[0];
  const float* bary    = (const float*)d_in[1];
  const float* view    = (const float*)d_in[2];
  const float* emb     = (const float*)d_in[3];
  const float* vde_W   = (const float*)d_in[4];
  const float* vde_b   = (const float*)d_in[5];
  const float* vh_W    = (const float*)d_in[6];
  const float* vh_b    = (const float*)d_in[7];
  const float* hid_W   = (const float*)d_in[8];
  const float* hid_b   = (const float*)d_in[9];
  const float* head_W0 = (const float*)d_in[10];
  const float* head_b0 = (const float*)d_in[11];
  const float* head_W1 = (const float*)d_in[12];
  const float* head_b1 = (const float*)d_in[13];
  const float* head_W2 = (const float*)d_in[14];
  const float* head_b2 = (const float*)d_in[15];
  u16* wsp = (u16*)d_ws;   // needs 397568 B

  rc_prep<<<777, 256, 0, stream>>>(vde_W, vh_W, hid_W, head_W0, head_W1, head_W2, wsp);
  rc_main<<<4096, 256, 0, stream>>>(vert, bary, view, emb, vde_b, vh_b, hid_b,
                                    head_b0, head_b1, head_b2, wsp, (float*)d_out);
}

// Round 2
// 449.243 us; speedup vs baseline: 1.5973x; 1.5973x over previous
//
#include <hip/hip_runtime.h>

typedef unsigned int  u32;
typedef unsigned short u16;
typedef __attribute__((ext_vector_type(8))) _Float16 h8;   // MFMA A/B frag: 8 fp16 = 4 VGPR
typedef __attribute__((ext_vector_type(4))) float    f4;   // MFMA C/D frag

#define RS   136   // padded row stride (fp16 elems): 272B rows, 16B-aligned, 2-way bank aliasing only
#define PRS  40    // padded row stride for vde weights (K=18 padded to 32, stored 40)
#define PIXB 128   // pixels per block (4 waves x 32 pixels)

__device__ __forceinline__ u16 f2h(float f) {
  _Float16 h = (_Float16)f;
  return __builtin_bit_cast(u16, h);
}
__device__ __forceinline__ float h2f(u16 u) {
  return (float)__builtin_bit_cast(_Float16, u);
}

// ---------------------------------------------------------------------------
// Prep: fp16 weights, transposed to [out][in], padded rows.
// ws layout (fp16 elems): [0,5120)          vdeT   [128][40]  (k<18 valid)
//                         [5120+i*17408)    11 x   [128][136] (vh0..2, hid00..12, headW0, headW1)
//                         [196608,198784)   head2T [16][136]  (n<4 valid)
// ---------------------------------------------------------------------------
__global__ __launch_bounds__(256) void rc_prep(
    const float* __restrict__ vde_W, const float* __restrict__ vh_W,
    const float* __restrict__ hid_W, const float* __restrict__ head_W0,
    const float* __restrict__ head_W1, const float* __restrict__ head_W2,
    u16* __restrict__ ws)
{
  const int VDE_N = 128 * PRS;          // 5120
  const int FULL  = 128 * RS;           // 17408
  const int TOT   = VDE_N + 11 * FULL + 16 * RS;  // 198784
  int i = blockIdx.x * 256 + threadIdx.x;
  if (i >= TOT) return;
  float val = 0.f;
  if (i < VDE_N) {
    int n = i / PRS, k = i - n * PRS;
    if (k < 18) val = vde_W[k * 128 + n];
  } else if (i < VDE_N + 11 * FULL) {
    int t = i - VDE_N;
    int j = t / FULL;
    int rr = t - j * FULL;
    int n = rr / RS, k = rr - n * RS;
    if (k < 128) {
      const float* src;
      if (j < 3)       src = vh_W  + j * 16384;
      else if (j < 9)  src = hid_W + (j - 3) * 16384;
      else if (j == 9) src = head_W0;
      else             src = head_W1;
      val = src[k * 128 + n];
    }
  } else {
    int t = i - (VDE_N + 11 * FULL);
    int n = t / RS, k = t - n * RS;
    if (k < 128 && n < 4) val = head_W2[k * 4 + n];
  }
  ws[i] = f2h(val);
}

// ---------------------------------------------------------------------------
// Main fused kernel, barrier-free main loop.
//   Block = 256 thr (4 waves), 128 pixels; wave w owns X rows [32w,32w+32) —
//   wave-private, so NO __syncthreads in the layer chain.
//   B-frags read directly from global ws (L1/L2-resident, shared by all waves).
//   LDS = X only (34 KB) -> 4 blocks/CU, 16 waves/CU.
// ---------------------------------------------------------------------------
__global__ __launch_bounds__(256, 4) void rc_main(
    const int*   __restrict__ vert,  const float* __restrict__ bary,
    const float* __restrict__ view,  const float* __restrict__ emb,
    const float* __restrict__ vde_b, const float* __restrict__ vh_b,
    const float* __restrict__ hid_b, const float* __restrict__ head_b0,
    const float* __restrict__ head_b1, const float* __restrict__ head_b2,
    const u16*   __restrict__ ws,    float* __restrict__ out)
{
  __shared__ __align__(16) u16 X[PIXB * RS];   // 34816 B, the only LDS

  const int tid  = threadIdx.x;
  const int lane = tid & 63;
  const int w    = tid >> 6;
  const int r    = lane & 15;       // B/C column within 16-tile; A row
  const int g    = lane >> 4;       // k-group; C row group
  const int pb   = w * 32;          // wave's first pixel row
  const size_t bpix = (size_t)blockIdx.x * PIXB;

  // ---- PE: lanes 0..31 compute their pixel's sin/cos encoding into X[row][0..32)
  if (lane < 32) {
    const int p = pb + lane;
    const float* vd = view + (bpix + p) * 3;
    const float SG0 = 6.28318530718f;   // 2pi / 0.9^0
    const float SG1 = 6.50777324f;      // 2pi / 0.9^(1/3)
    const float SG2 = 6.74038866f;      // 2pi / 0.9^(2/3)
    u32 pw[16];
#pragma unroll
    for (int i = 0; i < 3; ++i) {
      float x = vd[i];
      float s0 = __sinf(x * SG0), c0 = __cosf(x * SG0);
      float s1 = __sinf(x * SG1), c1 = __cosf(x * SG1);
      float s2 = __sinf(x * SG2), c2 = __cosf(x * SG2);
      pw[i * 3 + 0] = (u32)f2h(s0) | ((u32)f2h(s1) << 16);
      pw[i * 3 + 1] = (u32)f2h(s2) | ((u32)f2h(c0) << 16);
      pw[i * 3 + 2] = (u32)f2h(c1) | ((u32)f2h(c2) << 16);
    }
#pragma unroll
    for (int q = 9; q < 16; ++q) pw[q] = 0u;   // zero-pad k = 18..31
    uint4* dst = (uint4*)&X[p * RS];           // 272B rows -> 16B aligned
#pragma unroll
    for (int q = 0; q < 4; ++q)
      dst[q] = make_uint4(pw[4*q], pw[4*q+1], pw[4*q+2], pw[4*q+3]);
  }
  __syncthreads();   // once; main loop below is barrier-free

  // ---- L0: PE @ vde_W + vde_b (no relu) -> X
  {
    h8 a0 = *(const h8*)&X[(pb +      r) * RS + g * 8];
    h8 a1 = *(const h8*)&X[(pb + 16 + r) * RS + g * 8];
    const h8* bp = (const h8*)(ws + r * PRS + g * 8);   // 80B row stride: 16B aligned
#pragma unroll
    for (int nt = 0; nt < 8; ++nt) {
      h8 b = bp[nt * 80];                     // + nt*16 rows * 40 elems
      f4 z = {0.f, 0.f, 0.f, 0.f};
      f4 acc0 = __builtin_amdgcn_mfma_f32_16x16x32_f16(a0, b, z, 0, 0, 0);
      f4 acc1 = __builtin_amdgcn_mfma_f32_16x16x32_f16(a1, b, z, 0, 0, 0);
      float bv = vde_b[nt * 16 + r];
#pragma unroll
      for (int j = 0; j < 4; ++j) {
        X[(pb +      g * 4 + j) * RS + nt * 16 + r] = f2h(acc0[j] + bv);
        X[(pb + 16 + g * 4 + j) * RS + nt * 16 + r] = f2h(acc1[j] + bv);
      }
    }
  }

  // ---- 11 full 128x128 layers: li 0..2 = vh MLP, 3..8 = hidden, 9..10 = head
  u32 vhp[2][8][2] = {};   // captured vh (fp16 pairs): set at li==2, used at li==5
#pragma unroll 1
  for (int li = 0; li < 11; ++li) {
    const float* bias = (li < 3) ? (vh_b + li * 128)
                      : (li < 9) ? (hid_b + (li - 3) * 128)
                      : (li == 9) ? head_b0 : head_b1;
    const int mode = (li == 2) ? 1 : (li == 5) ? 2 : 0;  // 1=capture vh, 2=modulate

    h8 a[2][4];
#pragma unroll
    for (int mt = 0; mt < 2; ++mt)
#pragma unroll
      for (int ks = 0; ks < 4; ++ks)
        a[mt][ks] = *(const h8*)&X[(pb + mt * 16 + r) * RS + ks * 32 + g * 8];

    const h8* bp = (const h8*)(ws + 5120 + li * 17408 + r * RS + g * 8);
#pragma unroll
    for (int nt = 0; nt < 8; ++nt) {
      f4 acc[2] = {{0.f,0.f,0.f,0.f},{0.f,0.f,0.f,0.f}};
#pragma unroll
      for (int ks = 0; ks < 4; ++ks) {
        h8 b = bp[nt * 272 + ks * 4];         // (nt*16 rows)*136 + ks*32 elems
        acc[0] = __builtin_amdgcn_mfma_f32_16x16x32_f16(a[0][ks], b, acc[0], 0, 0, 0);
        acc[1] = __builtin_amdgcn_mfma_f32_16x16x32_f16(a[1][ks], b, acc[1], 0, 0, 0);
      }
      float bv = bias[nt * 16 + r];
#pragma unroll
      for (int mt = 0; mt < 2; ++mt) {
        float v0 = fmaxf(acc[mt][0] + bv, 0.f);
        float v1 = fmaxf(acc[mt][1] + bv, 0.f);
        float v2 = fmaxf(acc[mt][2] + bv, 0.f);
        float v3 = fmaxf(acc[mt][3] + bv, 0.f);
        if (mode == 1) {                       // vh = relu(out), keep in regs
          vhp[mt][nt][0] = (u32)f2h(v0) | ((u32)f2h(v1) << 16);
          vhp[mt][nt][1] = (u32)f2h(v2) | ((u32)f2h(v3) << 16);
        } else {
          if (mode == 2) {                     // h = relu(out) * vh
            v0 *= h2f((u16)(vhp[mt][nt][0] & 0xffffu));
            v1 *= h2f((u16)(vhp[mt][nt][0] >> 16));
            v2 *= h2f((u16)(vhp[mt][nt][1] & 0xffffu));
            v3 *= h2f((u16)(vhp[mt][nt][1] >> 16));
          }
          int base = (pb + mt * 16 + g * 4) * RS + nt * 16 + r;
          X[base]          = f2h(v0);
          X[base + RS]     = f2h(v1);
          X[base + 2 * RS] = f2h(v2);
          X[base + 3 * RS] = f2h(v3);
        }
      }
    }

    // ---- after vh capture: embedding gather+renorm+bary -> X (wave-private rows)
    if (li == 2) {
#pragma unroll 2
      for (int i = 0; i < 8; ++i) {
        int p = pb + g * 8 + i;                // 16-lane group g handles 8 pixels
        size_t gp = bpix + p;
        const int*   vi = vert + gp * 3;
        const float* by = bary + gp * 3;
        f4 va = {0.f,0.f,0.f,0.f}, vb = {0.f,0.f,0.f,0.f};
#pragma unroll
        for (int vt = 0; vt < 3; ++vt) {
          int id = vi[vt] + 1;
          const float* row = emb + (size_t)id * 128 + r * 8;  // lane r: 8 chans
          f4 e0 = *(const f4*)row;
          f4 e1 = *(const f4*)(row + 4);
          float ss = e0[0]*e0[0] + e0[1]*e0[1] + e0[2]*e0[2] + e0[3]*e0[3]
                   + e1[0]*e1[0] + e1[1]*e1[1] + e1[2]*e1[2] + e1[3]*e1[3];
          ss += __shfl_xor(ss, 1);             // reduce within the 16-lane group
          ss += __shfl_xor(ss, 2);
          ss += __shfl_xor(ss, 4);
          ss += __shfl_xor(ss, 8);
          float nrm = sqrtf(ss);
          float sc  = (nrm > 1.f) ? (1.f / (nrm + 1e-7f)) : 1.f;  // torch max_norm
          float wt  = by[vt] * sc;
#pragma unroll
          for (int j = 0; j < 4; ++j) { va[j] += wt * e0[j]; vb[j] += wt * e1[j]; }
        }
        h8 o;
#pragma unroll
        for (int j = 0; j < 4; ++j) { o[j] = (_Float16)va[j]; o[j+4] = (_Float16)vb[j]; }
        *(h8*)&X[p * RS + r * 8] = o;
      }
    }
  }

  // ---- L12: head_W2 (128 -> 4) + head_b2, no relu, write f32 output
  {
    h8 a[2][4];
#pragma unroll
    for (int mt = 0; mt < 2; ++mt)
#pragma unroll
      for (int ks = 0; ks < 4; ++ks)
        a[mt][ks] = *(const h8*)&X[(pb + mt * 16 + r) * RS + ks * 32 + g * 8];
    const h8* bp = (const h8*)(ws + 196608 + r * RS + g * 8);
    f4 acc0 = {0.f,0.f,0.f,0.f}, acc1 = {0.f,0.f,0.f,0.f};
#pragma unroll
    for (int ks = 0; ks < 4; ++ks) {
      h8 b = bp[ks * 4];
      acc0 = __builtin_amdgcn_mfma_f32_16x16x32_f16(a[0][ks], b, acc0, 0, 0, 0);
      acc1 = __builtin_amdgcn_mfma_f32_16x16x32_f16(a[1][ks], b, acc1, 0, 0, 0);
    }
    if (r < 4) {
      float bv = head_b2[r];
#pragma unroll
      for (int j = 0; j < 4; ++j) {
        out[(bpix + pb +      g * 4 + j) * 4 + r] = acc0[j] + bv;
        out[(bpix + pb + 16 + g * 4 + j) * 4 + r] = acc1[j] + bv;
      }
    }
  }
}

// ---------------------------------------------------------------------------
extern "C" void kernel_launch(void* const* d_in, const int* in_sizes, int n_in,
                              void* d_out, int out_size, void* d_ws, size_t ws_size,
                              hipStream_t stream) {
  const int*   vert    = (const int*)  d_in[0];
  const float* bary    = (const float*)d_in[1];
  const float* view    = (const float*)d_in[2];
  const float* emb     = (const float*)d_in[3];
  const float* vde_W   = (const float*)d_in[4];
  const float* vde_b   = (const float*)d_in[5];
  const float* vh_W    = (const float*)d_in[6];
  const float* vh_b    = (const float*)d_in[7];
  const float* hid_W   = (const float*)d_in[8];
  const float* hid_b   = (const float*)d_in[9];
  const float* head_W0 = (const float*)d_in[10];
  const float* head_b0 = (const float*)d_in[11];
  const float* head_W1 = (const float*)d_in[12];
  const float* head_b1 = (const float*)d_in[13];
  const float* head_W2 = (const float*)d_in[14];
  const float* head_b2 = (const float*)d_in[15];
  u16* wsp = (u16*)d_ws;   // needs 397568 B

  rc_prep<<<777, 256, 0, stream>>>(vde_W, vh_W, hid_W, head_W0, head_W1, head_W2, wsp);
  rc_main<<<4096, 256, 0, stream>>>(vert, bary, view, emb, vde_b, vh_b, hid_b,
                                    head_b0, head_b1, head_b2, wsp, (float*)d_out);
}